// Round 1
// baseline (127.468 us; speedup 1.0000x reference)
//
#include <hip/hip_runtime.h>

#define NQ 16384
#define NKV 4096
#define DD 8
#define EPSF 1e-5f
#define SCALE 0.35355339059327373f   // 1/sqrt(8)
#define KG 32                        // lanes (key-groups) per query
#define QT 4                         // queries register-tiled per thread

__device__ __forceinline__ float dot8(float4 a1, float4 a2, float4 b1, float4 b2) {
    return a1.x*b1.x + a1.y*b1.y + a1.z*b1.z + a1.w*b1.w
         + a2.x*b2.x + a2.y*b2.y + a2.z*b2.z + a2.w*b2.w;
}

// ---------------- Kernel A: LN + Q/K/V projections ----------------
__global__ void preproc_kernel(const float* __restrict__ x, const float* __restrict__ y,
                               const float* __restrict__ Wq, const float* __restrict__ Wk,
                               const float* __restrict__ Wv, const float* __restrict__ ln_w,
                               const float* __restrict__ ln_b,
                               float* __restrict__ XQ, float* __restrict__ YK,
                               float* __restrict__ YV) {
    int row = blockIdx.x * blockDim.x + threadIdx.x;
    if (row >= NQ + NKV) return;
    bool is_x = row < NQ;
    const float* src = is_x ? (x + (size_t)row * DD) : (y + (size_t)(row - NQ) * DD);
    float4 a = ((const float4*)src)[0];
    float4 b = ((const float4*)src)[1];
    float t[8] = {a.x,a.y,a.z,a.w,b.x,b.y,b.z,b.w};
    float mu = 0.f;
    #pragma unroll
    for (int i = 0; i < 8; i++) mu += t[i];
    mu *= 0.125f;
    float var = 0.f;
    #pragma unroll
    for (int i = 0; i < 8; i++) { float d = t[i] - mu; var += d * d; }
    var *= 0.125f;
    float rs = rsqrtf(var + EPSF);
    float z[8];
    #pragma unroll
    for (int i = 0; i < 8; i++) z[i] = (t[i] - mu) * rs * ln_w[i] + ln_b[i];

    if (is_x) {
        float o[8];
        #pragma unroll
        for (int oo = 0; oo < 8; oo++) {
            float acc = 0.f;
            #pragma unroll
            for (int i = 0; i < 8; i++) acc += Wq[oo*8+i] * z[i];
            o[oo] = acc;
        }
        float4* dst = (float4*)(XQ + (size_t)row * 8);
        dst[0] = make_float4(o[0],o[1],o[2],o[3]);
        dst[1] = make_float4(o[4],o[5],o[6],o[7]);
    } else {
        int r = row - NQ;
        float ok[8], ov[8];
        #pragma unroll
        for (int oo = 0; oo < 8; oo++) {
            float ak = 0.f, av = 0.f;
            #pragma unroll
            for (int i = 0; i < 8; i++) { ak += Wk[oo*8+i]*z[i]; av += Wv[oo*8+i]*z[i]; }
            ok[oo] = ak; ov[oo] = av;
        }
        float4* dk = (float4*)(YK + (size_t)r * 8);
        dk[0] = make_float4(ok[0],ok[1],ok[2],ok[3]);
        dk[1] = make_float4(ok[4],ok[5],ok[6],ok[7]);
        float4* dv = (float4*)(YV + (size_t)r * 8);
        dv[0] = make_float4(ov[0],ov[1],ov[2],ov[3]);
        dv[1] = make_float4(ov[4],ov[5],ov[6],ov[7]);
    }
}

// ---------------- Kernel B: fused smooth-softmax attention + residual 1 ----------------
// Layout: tid = qslot*32 + kg. 32 lanes (kg) split the 4096 keys (interleaved for
// coalescing); each thread handles QT=4 queries. Two passes: (1) true max,
// (2) exp/relu accumulation. Butterfly shuffle combines across the 32 lanes.
__global__ __launch_bounds__(256) void attn_kernel(
        const float* __restrict__ XQ, const float* __restrict__ YK,
        const float* __restrict__ YV, const float* __restrict__ x,
        float* __restrict__ Z1) {
    const int tid = threadIdx.x;
    const int qslot = tid >> 5;       // 0..7
    const int kg = tid & 31;          // 0..31
    const int qbase = blockIdx.x * ((256/KG)*QT) + qslot * QT;   // 32 queries / block

    float4 qa[QT], qb[QT];
    #pragma unroll
    for (int t = 0; t < QT; t++) {
        const float4* qp = (const float4*)(XQ + (size_t)(qbase + t) * 8);
        qa[t] = qp[0]; qb[t] = qp[1];
    }

    const int NITER = NKV / KG;       // 128
    float mx[QT];
    #pragma unroll
    for (int t = 0; t < QT; t++) mx[t] = -1e30f;

    // pass 1: row max
    for (int j = 0; j < NITER; j++) {
        int krow = kg + j * KG;       // interleaved -> coalesced wave loads
        const float4* kp = (const float4*)(YK + (size_t)krow * 8);
        float4 ka = kp[0], kb = kp[1];
        #pragma unroll
        for (int t = 0; t < QT; t++) {
            float s = dot8(qa[t], qb[t], ka, kb) * SCALE;
            mx[t] = fmaxf(mx[t], s);
        }
    }
    #pragma unroll
    for (int m = 16; m >= 1; m >>= 1) {
        #pragma unroll
        for (int t = 0; t < QT; t++)
            mx[t] = fmaxf(mx[t], __shfl_xor(mx[t], m));
    }

    // pass 2: exp + relu accumulation
    float Z[QT], R[QT], A[QT][8], B[QT][8];
    #pragma unroll
    for (int t = 0; t < QT; t++) {
        Z[t] = 0.f; R[t] = 0.f;
        #pragma unroll
        for (int c = 0; c < 8; c++) { A[t][c] = 0.f; B[t][c] = 0.f; }
    }
    for (int j = 0; j < NITER; j++) {
        int krow = kg + j * KG;
        const float4* kp = (const float4*)(YK + (size_t)krow * 8);
        float4 ka = kp[0], kb = kp[1];
        const float4* vp = (const float4*)(YV + (size_t)krow * 8);
        float4 va = vp[0], vb = vp[1];
        float v[8] = {va.x,va.y,va.z,va.w,vb.x,vb.y,vb.z,vb.w};
        #pragma unroll
        for (int t = 0; t < QT; t++) {
            float s = dot8(qa[t], qb[t], ka, kb) * SCALE;
            float e = __expf(s - mx[t]);
            float rl = fmaxf(s, 0.f);
            Z[t] += e; R[t] += rl;
            #pragma unroll
            for (int c = 0; c < 8; c++) {
                A[t][c] += e * v[c];
                B[t][c] += rl * v[c];
            }
        }
    }

    // butterfly sum-reduce over the 32 kg lanes
    #pragma unroll
    for (int m = 16; m >= 1; m >>= 1) {
        #pragma unroll
        for (int t = 0; t < QT; t++) {
            Z[t] += __shfl_xor(Z[t], m);
            R[t] += __shfl_xor(R[t], m);
            #pragma unroll
            for (int c = 0; c < 8; c++) {
                A[t][c] += __shfl_xor(A[t][c], m);
                B[t][c] += __shfl_xor(B[t][c], m);
            }
        }
    }

    if (kg == 0) {
        #pragma unroll
        for (int t = 0; t < QT; t++) {
            int row = qbase + t;
            const float4* xp = (const float4*)(x + (size_t)row * 8);
            float4 xa = xp[0], xb = xp[1];
            float xr[8] = {xa.x,xa.y,xa.z,xa.w,xb.x,xb.y,xb.z,xb.w};
            float iz  = 1.0f / Z[t];
            float den = 1.0f / (0.1f * R[t] + 1.0f);
            float o[8];
            #pragma unroll
            for (int c = 0; c < 8; c++)
                o[c] = (0.1f * B[t][c] + A[t][c] * iz) * den + xr[c];
            float4* zp = (float4*)(Z1 + (size_t)row * 8);
            zp[0] = make_float4(o[0],o[1],o[2],o[3]);
            zp[1] = make_float4(o[4],o[5],o[6],o[7]);
        }
    }
}

// ---------------- Kernel C: LN + MLP (8->64->64->8) + residual 2 ----------------
// 4 threads per row; each handles 16 of the 64 hidden-2 units (layer1 recomputed,
// layers 2+3 fused so no h2 array); shuffle-combine the 8 output partials.
__global__ __launch_bounds__(256) void mlp_kernel(
        const float* __restrict__ Z1,
        const float* __restrict__ W1, const float* __restrict__ b1,
        const float* __restrict__ W2, const float* __restrict__ b2,
        const float* __restrict__ W3, const float* __restrict__ b3,
        const float* __restrict__ ln_w, const float* __restrict__ ln_b,
        float* __restrict__ out) {
    __shared__ float W1s[512], W2s[4096], W3s[512], b1s[64], b2s[64], b3s[8], lw[8], lb[8];
    for (int i = threadIdx.x; i < 512; i += 256) { W1s[i] = W1[i]; W3s[i] = W3[i]; }
    for (int i = threadIdx.x; i < 4096; i += 256) W2s[i] = W2[i];
    if (threadIdx.x < 64) { b1s[threadIdx.x] = b1[threadIdx.x]; b2s[threadIdx.x] = b2[threadIdx.x]; }
    if (threadIdx.x < 8) { b3s[threadIdx.x] = b3[threadIdx.x]; lw[threadIdx.x] = ln_w[threadIdx.x]; lb[threadIdx.x] = ln_b[threadIdx.x]; }
    __syncthreads();

    int gid = blockIdx.x * 256 + threadIdx.x;
    int row = gid >> 2;
    int og  = threadIdx.x & 3;        // 16 hidden-2 units each

    const float4* zp = (const float4*)(Z1 + (size_t)row * 8);
    float4 a = zp[0], b = zp[1];
    float z1r[8] = {a.x,a.y,a.z,a.w,b.x,b.y,b.z,b.w};
    float mu = 0.f;
    #pragma unroll
    for (int i = 0; i < 8; i++) mu += z1r[i];
    mu *= 0.125f;
    float var = 0.f;
    #pragma unroll
    for (int i = 0; i < 8; i++) { float d = z1r[i] - mu; var += d * d; }
    var *= 0.125f;
    float rs = rsqrtf(var + EPSF);
    float z2[8];
    #pragma unroll
    for (int i = 0; i < 8; i++) z2[i] = (z1r[i] - mu) * rs * lw[i] + lb[i];

    // layer 1 (full, recomputed per og-thread), h kept in registers
    float h[64];
    #pragma unroll
    for (int o = 0; o < 64; o++) {
        float acc = b1s[o];
        #pragma unroll
        for (int i = 0; i < 8; i++) acc += W1s[o*8+i] * z2[i];
        h[o] = fmaxf(acc, 0.f);
    }

    // layers 2+3 fused over this thread's 16 hidden-2 units
    float oacc[8];
    #pragma unroll
    for (int d = 0; d < 8; d++) oacc[d] = 0.f;
    int obase = og * 16;
    for (int oo = 0; oo < 16; oo++) {
        int o = obase + oo;
        float a0 = 0.f, a1 = 0.f, a2 = 0.f, a3 = 0.f;
        const float4* w2r = (const float4*)(W2s + o * 64);
        #pragma unroll
        for (int i4 = 0; i4 < 16; i4++) {
            float4 w = w2r[i4];
            a0 += w.x * h[4*i4];   a1 += w.y * h[4*i4+1];
            a2 += w.z * h[4*i4+2]; a3 += w.w * h[4*i4+3];
        }
        float act = fmaxf(b2s[o] + ((a0 + a1) + (a2 + a3)), 0.f);
        #pragma unroll
        for (int d = 0; d < 8; d++) oacc[d] += W3s[d*64+o] * act;
    }

    // combine the 4 og-partials (lanes gid, gid^1, gid^2 are adjacent)
    #pragma unroll
    for (int m = 1; m <= 2; m <<= 1) {
        #pragma unroll
        for (int d = 0; d < 8; d++) oacc[d] += __shfl_xor(oacc[d], m);
    }
    if (og == 0) {
        float4* op = (float4*)(out + (size_t)row * 8);
        op[0] = make_float4(oacc[0]+b3s[0]+z1r[0], oacc[1]+b3s[1]+z1r[1],
                            oacc[2]+b3s[2]+z1r[2], oacc[3]+b3s[3]+z1r[3]);
        op[1] = make_float4(oacc[4]+b3s[4]+z1r[4], oacc[5]+b3s[5]+z1r[5],
                            oacc[6]+b3s[6]+z1r[6], oacc[7]+b3s[7]+z1r[7]);
    }
}

extern "C" void kernel_launch(void* const* d_in, const int* in_sizes, int n_in,
                              void* d_out, int out_size, void* d_ws, size_t ws_size,
                              hipStream_t stream) {
    const float* x   = (const float*)d_in[0];
    const float* y   = (const float*)d_in[1];
    const float* Wq  = (const float*)d_in[2];
    const float* Wk  = (const float*)d_in[3];
    const float* Wv  = (const float*)d_in[4];
    const float* W1  = (const float*)d_in[5];
    const float* b1  = (const float*)d_in[6];
    const float* W2  = (const float*)d_in[7];
    const float* b2  = (const float*)d_in[8];
    const float* W3  = (const float*)d_in[9];
    const float* b3  = (const float*)d_in[10];
    const float* lnw = (const float*)d_in[11];
    const float* lnb = (const float*)d_in[12];

    float* ws = (float*)d_ws;
    float* XQ = ws;                 // 131072 floats
    float* YK = ws + 131072;        // 32768
    float* YV = ws + 163840;        // 32768
    float* Z1 = ws + 196608;        // 131072
    float* out = (float*)d_out;

    preproc_kernel<<<(NQ + NKV + 255) / 256, 256, 0, stream>>>(x, y, Wq, Wk, Wv, lnw, lnb, XQ, YK, YV);
    attn_kernel<<<NQ / 32, 256, 0, stream>>>(XQ, YK, YV, x, Z1);
    mlp_kernel<<<(NQ * 4) / 256, 256, 0, stream>>>(Z1, W1, b1, W2, b2, W3, b3, lnw, lnb, out);
}

// Round 2
// 69.859 us; speedup vs baseline: 1.8246x; 1.8246x over previous
//
#include <hip/hip_runtime.h>
#include <hip/hip_bf16.h>

#define NQ 16384
#define NKV 4096
#define EPSF 1e-5f
#define SCALE 0.35355339059327373f   // 1/sqrt(8), folded into K-hat

typedef float f32x4 __attribute__((ext_vector_type(4)));
typedef short s16x4 __attribute__((ext_vector_type(4)));

union U2S4 { uint2 u; s16x4 s; };

#if __has_builtin(__builtin_amdgcn_mfma_f32_16x16x16bf16_1k)
#define MFMA16(a, b, c) __builtin_amdgcn_mfma_f32_16x16x16bf16_1k((a), (b), (c), 0, 0, 0)
#else
static __device__ __forceinline__ f32x4 mfma16_asm(s16x4 a, s16x4 b, f32x4 c) {
    asm volatile("v_mfma_f32_16x16x16_bf16 %0, %1, %2, %0" : "+v"(c) : "v"(a), "v"(b));
    return c;
}
#define MFMA16(a, b, c) mfma16_asm((a), (b), (c))
#endif

__device__ __forceinline__ unsigned int pk_bf16(float a, float b) {
    __hip_bfloat162 h = __float22bfloat162_rn(make_float2(a, b));
    return *reinterpret_cast<unsigned int*>(&h);
}

// ---------------- Kernel A: LN + Q/K/V projections -> bf16 fragments ----------------
// QH: [16384][16] bf16 (cols 8..15 zero)      row-major
// KH: [4096][16] bf16 (scaled by 1/sqrt8, cols 8..15 zero)
// VT: [16][4096] bf16 d-major (rows 8..15 unused garbage, never consumed)
__global__ void preproc_kernel(const float* __restrict__ x, const float* __restrict__ y,
                               const float* __restrict__ Wq, const float* __restrict__ Wk,
                               const float* __restrict__ Wv, const float* __restrict__ ln_w,
                               const float* __restrict__ ln_b,
                               ushort* __restrict__ QH, ushort* __restrict__ KH,
                               ushort* __restrict__ VT) {
    int row = blockIdx.x * blockDim.x + threadIdx.x;
    if (row >= NQ + NKV) return;
    bool is_x = row < NQ;
    const float* src = is_x ? (x + (size_t)row * 8) : (y + (size_t)(row - NQ) * 8);
    float4 a = ((const float4*)src)[0];
    float4 b = ((const float4*)src)[1];
    float t[8] = {a.x,a.y,a.z,a.w,b.x,b.y,b.z,b.w};
    float mu = 0.f;
    #pragma unroll
    for (int i = 0; i < 8; i++) mu += t[i];
    mu *= 0.125f;
    float var = 0.f;
    #pragma unroll
    for (int i = 0; i < 8; i++) { float d = t[i] - mu; var += d * d; }
    var *= 0.125f;
    float rs = rsqrtf(var + EPSF);
    float z[8];
    #pragma unroll
    for (int i = 0; i < 8; i++) z[i] = (t[i] - mu) * rs * ln_w[i] + ln_b[i];

    if (is_x) {
        float o[8];
        #pragma unroll
        for (int oo = 0; oo < 8; oo++) {
            float acc = 0.f;
            #pragma unroll
            for (int i = 0; i < 8; i++) acc += Wq[oo*8+i] * z[i];
            o[oo] = acc;
        }
        uint4 lo, hi;
        lo.x = pk_bf16(o[0],o[1]); lo.y = pk_bf16(o[2],o[3]);
        lo.z = pk_bf16(o[4],o[5]); lo.w = pk_bf16(o[6],o[7]);
        hi.x = hi.y = hi.z = hi.w = 0u;
        uint4* dst = (uint4*)(QH + (size_t)row * 16);
        dst[0] = lo; dst[1] = hi;
    } else {
        int r = row - NQ;
        float ok[8], ov[8];
        #pragma unroll
        for (int oo = 0; oo < 8; oo++) {
            float ak = 0.f, av = 0.f;
            #pragma unroll
            for (int i = 0; i < 8; i++) { ak += Wk[oo*8+i]*z[i]; av += Wv[oo*8+i]*z[i]; }
            ok[oo] = ak * SCALE; ov[oo] = av;
        }
        uint4 lo, hi;
        lo.x = pk_bf16(ok[0],ok[1]); lo.y = pk_bf16(ok[2],ok[3]);
        lo.z = pk_bf16(ok[4],ok[5]); lo.w = pk_bf16(ok[6],ok[7]);
        hi.x = hi.y = hi.z = hi.w = 0u;
        uint4* dst = (uint4*)(KH + (size_t)r * 16);
        dst[0] = lo; dst[1] = hi;
        #pragma unroll
        for (int d = 0; d < 8; d++) {
            __hip_bfloat16 hb = __float2bfloat16(ov[d]);
            VT[(size_t)d * NKV + r] = *reinterpret_cast<ushort*>(&hb);
        }
    }
}

// ---------------- Kernel B: MFMA smooth-softmax attention + residual 1 ----------------
// Block = 4 waves, one 16-query tile; wave w handles keys [w*1024, w*1024+1024).
// S^T tile via mfma(A=K-frag, B=Q-frag): C row = key(4*grp+reg), col = query(lane&15).
// That C layout IS the B-operand layout, so exp/relu results feed the PV mfmas
// (O^T += V^T-frag * P^T) directly after bf16 packing. LDS combine across 4 waves.
__global__ __launch_bounds__(256) void attn_kernel(
        const ushort* __restrict__ QH, const ushort* __restrict__ KH,
        const ushort* __restrict__ VT, const float* __restrict__ x,
        float* __restrict__ Z1) {
    __shared__ float Le[4][64][4];
    __shared__ float Lr[4][64][4];
    __shared__ float Lz[4][64];
    __shared__ float LR[4][64];

    const int tid  = threadIdx.x;
    const int w    = tid >> 6;
    const int lane = tid & 63;
    const int grp  = lane >> 4;
    const int qi   = lane & 15;
    const int q0   = blockIdx.x * 16;

    U2S4 qf;
    qf.u = *(const uint2*)(QH + (size_t)(q0 + qi) * 16 + 4 * grp);

    const ushort* kp = KH + (size_t)(w * 1024 + qi) * 16 + 4 * grp;
    const ushort* vp = VT + (size_t)qi * NKV + w * 1024 + 4 * grp;

    f32x4 ae = {0.f,0.f,0.f,0.f};
    f32x4 ar = {0.f,0.f,0.f,0.f};
    float Zp = 0.f, Rp = 0.f;

    #pragma unroll 4
    for (int t = 0; t < 64; t++) {
        U2S4 kf; kf.u = *(const uint2*)kp;
        U2S4 vf; vf.u = *(const uint2*)vp;
        kp += 16 * 16;   // next 16 key rows
        vp += 16;        // next 16 key cols

        f32x4 s = MFMA16(kf.s, qf.s, ((f32x4){0.f,0.f,0.f,0.f}));

        float e0 = __expf(s[0]), e1 = __expf(s[1]);
        float e2 = __expf(s[2]), e3 = __expf(s[3]);
        float r0 = fmaxf(s[0], 0.f), r1 = fmaxf(s[1], 0.f);
        float r2 = fmaxf(s[2], 0.f), r3 = fmaxf(s[3], 0.f);
        Zp += (e0 + e1) + (e2 + e3);
        Rp += (r0 + r1) + (r2 + r3);

        U2S4 pe; pe.u.x = pk_bf16(e0, e1); pe.u.y = pk_bf16(e2, e3);
        U2S4 pr; pr.u.x = pk_bf16(r0, r1); pr.u.y = pk_bf16(r2, r3);

        ae = MFMA16(vf.s, pe.s, ae);
        ar = MFMA16(vf.s, pr.s, ar);
    }

    // combine the 4 lane-groups (key sub-ranges) of Z/R within the wave
    Zp += __shfl_xor(Zp, 16); Zp += __shfl_xor(Zp, 32);
    Rp += __shfl_xor(Rp, 16); Rp += __shfl_xor(Rp, 32);

    Lz[w][lane] = Zp;
    LR[w][lane] = Rp;
    #pragma unroll
    for (int r = 0; r < 4; r++) { Le[w][lane][r] = ae[r]; Lr[w][lane][r] = ar[r]; }
    __syncthreads();

    if (tid < 32) {           // groups 0,1 cover d = 0..7
        const int l = tid, g = l >> 4, q = l & 15;
        f32x4 Ae = {0.f,0.f,0.f,0.f}, Ar = {0.f,0.f,0.f,0.f};
        float Z = 0.f, R = 0.f;
        #pragma unroll
        for (int w2 = 0; w2 < 4; w2++) {
            Z += Lz[w2][l]; R += LR[w2][l];
            #pragma unroll
            for (int r = 0; r < 4; r++) { Ae[r] += Le[w2][l][r]; Ar[r] += Lr[w2][l][r]; }
        }
        float iz  = 1.0f / Z;
        float den = 1.0f / (0.1f * R + 1.0f);
        #pragma unroll
        for (int r = 0; r < 4; r++) {
            int d = 4 * g + r;
            size_t idx = (size_t)(q0 + q) * 8 + d;
            Z1[idx] = (0.1f * Ar[r] + Ae[r] * iz) * den + x[idx];
        }
    }
}

// ---------------- Kernel C: LN + MLP (8->64->64->8) + residual 2 ----------------
__global__ __launch_bounds__(256) void mlp_kernel(
        const float* __restrict__ Z1,
        const float* __restrict__ W1, const float* __restrict__ b1,
        const float* __restrict__ W2, const float* __restrict__ b2,
        const float* __restrict__ W3, const float* __restrict__ b3,
        const float* __restrict__ ln_w, const float* __restrict__ ln_b,
        float* __restrict__ out) {
    __shared__ float W1s[512], W2s[4096], W3s[512], b1s[64], b2s[64], b3s[8], lw[8], lb[8];
    for (int i = threadIdx.x; i < 512; i += 256) { W1s[i] = W1[i]; W3s[i] = W3[i]; }
    for (int i = threadIdx.x; i < 4096; i += 256) W2s[i] = W2[i];
    if (threadIdx.x < 64) { b1s[threadIdx.x] = b1[threadIdx.x]; b2s[threadIdx.x] = b2[threadIdx.x]; }
    if (threadIdx.x < 8) { b3s[threadIdx.x] = b3[threadIdx.x]; lw[threadIdx.x] = ln_w[threadIdx.x]; lb[threadIdx.x] = ln_b[threadIdx.x]; }
    __syncthreads();

    int gid = blockIdx.x * 256 + threadIdx.x;
    int row = gid >> 2;
    int og  = threadIdx.x & 3;

    const float4* zp = (const float4*)(Z1 + (size_t)row * 8);
    float4 a = zp[0], b = zp[1];
    float z1r[8] = {a.x,a.y,a.z,a.w,b.x,b.y,b.z,b.w};
    float mu = 0.f;
    #pragma unroll
    for (int i = 0; i < 8; i++) mu += z1r[i];
    mu *= 0.125f;
    float var = 0.f;
    #pragma unroll
    for (int i = 0; i < 8; i++) { float d = z1r[i] - mu; var += d * d; }
    var *= 0.125f;
    float rs = rsqrtf(var + EPSF);
    float z2[8];
    #pragma unroll
    for (int i = 0; i < 8; i++) z2[i] = (z1r[i] - mu) * rs * lw[i] + lb[i];

    float h[64];
    #pragma unroll
    for (int o = 0; o < 64; o++) {
        float acc = b1s[o];
        #pragma unroll
        for (int i = 0; i < 8; i++) acc += W1s[o*8+i] * z2[i];
        h[o] = fmaxf(acc, 0.f);
    }

    float oacc[8];
    #pragma unroll
    for (int d = 0; d < 8; d++) oacc[d] = 0.f;
    int obase = og * 16;
    for (int oo = 0; oo < 16; oo++) {
        int o = obase + oo;
        float a0 = 0.f, a1 = 0.f, a2 = 0.f, a3 = 0.f;
        const float4* w2r = (const float4*)(W2s + o * 64);
        #pragma unroll
        for (int i4 = 0; i4 < 16; i4++) {
            float4 wv = w2r[i4];
            a0 += wv.x * h[4*i4];   a1 += wv.y * h[4*i4+1];
            a2 += wv.z * h[4*i4+2]; a3 += wv.w * h[4*i4+3];
        }
        float act = fmaxf(b2s[o] + ((a0 + a1) + (a2 + a3)), 0.f);
        #pragma unroll
        for (int d = 0; d < 8; d++) oacc[d] += W3s[d*64+o] * act;
    }

    #pragma unroll
    for (int m = 1; m <= 2; m <<= 1) {
        #pragma unroll
        for (int d = 0; d < 8; d++) oacc[d] += __shfl_xor(oacc[d], m);
    }
    if (og == 0) {
        float4* op = (float4*)(out + (size_t)row * 8);
        op[0] = make_float4(oacc[0]+b3s[0]+z1r[0], oacc[1]+b3s[1]+z1r[1],
                            oacc[2]+b3s[2]+z1r[2], oacc[3]+b3s[3]+z1r[3]);
        op[1] = make_float4(oacc[4]+b3s[4]+z1r[4], oacc[5]+b3s[5]+z1r[5],
                            oacc[6]+b3s[6]+z1r[6], oacc[7]+b3s[7]+z1r[7]);
    }
}

extern "C" void kernel_launch(void* const* d_in, const int* in_sizes, int n_in,
                              void* d_out, int out_size, void* d_ws, size_t ws_size,
                              hipStream_t stream) {
    const float* x   = (const float*)d_in[0];
    const float* y   = (const float*)d_in[1];
    const float* Wq  = (const float*)d_in[2];
    const float* Wk  = (const float*)d_in[3];
    const float* Wv  = (const float*)d_in[4];
    const float* W1  = (const float*)d_in[5];
    const float* b1  = (const float*)d_in[6];
    const float* W2  = (const float*)d_in[7];
    const float* b2  = (const float*)d_in[8];
    const float* W3  = (const float*)d_in[9];
    const float* b3  = (const float*)d_in[10];
    const float* lnw = (const float*)d_in[11];
    const float* lnb = (const float*)d_in[12];

    char* ws = (char*)d_ws;
    ushort* QH = (ushort*)ws;                 // 524288 B
    ushort* KH = (ushort*)(ws + 524288);      // 131072 B
    ushort* VT = (ushort*)(ws + 655360);      // 131072 B
    float*  Z1 = (float*)(ws + 786432);       // 524288 B
    float* out = (float*)d_out;

    preproc_kernel<<<(NQ + NKV + 255) / 256, 256, 0, stream>>>(x, y, Wq, Wk, Wv, lnw, lnb, QH, KH, VT);
    attn_kernel<<<NQ / 16, 256, 0, stream>>>(QH, KH, VT, x, Z1);
    mlp_kernel<<<(NQ * 4) / 256, 256, 0, stream>>>(Z1, W1, b1, W2, b2, W3, b3, lnw, lnb, out);
}

// Round 3
// 58.706 us; speedup vs baseline: 2.1713x; 1.1900x over previous
//
#include <hip/hip_runtime.h>
#include <hip/hip_bf16.h>

#define NQ 16384
#define NKV 4096
#define EPSF 1e-5f
// 1/sqrt(8) * log2(e): folds the exp2 conversion into K-hat
#define SCALE2 0.5100604576761344f
// 0.1 / log2(e) = 0.1*ln2: compensates relu weights scaled by log2e
#define C1 0.06931471805599453f

typedef float f32x4 __attribute__((ext_vector_type(4)));
typedef short s16x4 __attribute__((ext_vector_type(4)));

union U2S4 { uint2 u; s16x4 s; };

#if __has_builtin(__builtin_amdgcn_mfma_f32_16x16x16bf16_1k)
#define MFMA16(a, b, c) __builtin_amdgcn_mfma_f32_16x16x16bf16_1k((a), (b), (c), 0, 0, 0)
#else
static __device__ __forceinline__ f32x4 mfma16_asm(s16x4 a, s16x4 b, f32x4 c) {
    asm volatile("v_mfma_f32_16x16x16_bf16 %0, %1, %2, %0" : "+v"(c) : "v"(a), "v"(b));
    return c;
}
#define MFMA16(a, b, c) mfma16_asm((a), (b), (c))
#endif

#if __has_builtin(__builtin_amdgcn_exp2f)
#define EXP2F(x) __builtin_amdgcn_exp2f(x)
#else
#define EXP2F(x) exp2f(x)
#endif

__device__ __forceinline__ unsigned int pk_bf16(float a, float b) {
    __hip_bfloat162 h = __float22bfloat162_rn(make_float2(a, b));
    return *reinterpret_cast<unsigned int*>(&h);
}

// ---------------- Kernel A: LN + Q/K/V projections -> bf16 fragments ----------------
// QH: [16384][16] bf16 (cols 8..15 zero)
// KH: [4096][16] bf16 (scaled by log2e/sqrt8, cols 8..15 zero)
// VT: [16][4096] bf16 d-major; row 8 = ones (Z/R via MFMA), rows 9..15 = 0
__global__ void preproc_kernel(const float* __restrict__ x, const float* __restrict__ y,
                               const float* __restrict__ Wq, const float* __restrict__ Wk,
                               const float* __restrict__ Wv, const float* __restrict__ ln_w,
                               const float* __restrict__ ln_b,
                               ushort* __restrict__ QH, ushort* __restrict__ KH,
                               ushort* __restrict__ VT) {
    int row = blockIdx.x * blockDim.x + threadIdx.x;
    if (row >= NQ + NKV) return;
    bool is_x = row < NQ;
    const float* src = is_x ? (x + (size_t)row * 8) : (y + (size_t)(row - NQ) * 8);
    float4 a = ((const float4*)src)[0];
    float4 b = ((const float4*)src)[1];
    float t[8] = {a.x,a.y,a.z,a.w,b.x,b.y,b.z,b.w};
    float mu = 0.f;
    #pragma unroll
    for (int i = 0; i < 8; i++) mu += t[i];
    mu *= 0.125f;
    float var = 0.f;
    #pragma unroll
    for (int i = 0; i < 8; i++) { float d = t[i] - mu; var += d * d; }
    var *= 0.125f;
    float rs = rsqrtf(var + EPSF);
    float z[8];
    #pragma unroll
    for (int i = 0; i < 8; i++) z[i] = (t[i] - mu) * rs * ln_w[i] + ln_b[i];

    if (is_x) {
        float o[8];
        #pragma unroll
        for (int oo = 0; oo < 8; oo++) {
            float acc = 0.f;
            #pragma unroll
            for (int i = 0; i < 8; i++) acc += Wq[oo*8+i] * z[i];
            o[oo] = acc;
        }
        uint4 lo, hi;
        lo.x = pk_bf16(o[0],o[1]); lo.y = pk_bf16(o[2],o[3]);
        lo.z = pk_bf16(o[4],o[5]); lo.w = pk_bf16(o[6],o[7]);
        hi.x = hi.y = hi.z = hi.w = 0u;
        uint4* dst = (uint4*)(QH + (size_t)row * 16);
        dst[0] = lo; dst[1] = hi;
    } else {
        int r = row - NQ;
        float ok[8], ov[8];
        #pragma unroll
        for (int oo = 0; oo < 8; oo++) {
            float ak = 0.f, av = 0.f;
            #pragma unroll
            for (int i = 0; i < 8; i++) { ak += Wk[oo*8+i]*z[i]; av += Wv[oo*8+i]*z[i]; }
            ok[oo] = ak * SCALE2; ov[oo] = av;
        }
        uint4 lo, hi;
        lo.x = pk_bf16(ok[0],ok[1]); lo.y = pk_bf16(ok[2],ok[3]);
        lo.z = pk_bf16(ok[4],ok[5]); lo.w = pk_bf16(ok[6],ok[7]);
        hi.x = hi.y = hi.z = hi.w = 0u;
        uint4* dst = (uint4*)(KH + (size_t)r * 16);
        dst[0] = lo; dst[1] = hi;
        #pragma unroll
        for (int d = 0; d < 8; d++) {
            __hip_bfloat16 hb = __float2bfloat16(ov[d]);
            VT[(size_t)d * NKV + r] = *reinterpret_cast<ushort*>(&hb);
        }
        VT[(size_t)8 * NKV + r] = 0x3F80;   // 1.0 bf16 -> Z/R rows
        #pragma unroll
        for (int d = 9; d < 16; d++) VT[(size_t)d * NKV + r] = 0;
    }
}

// ---------------- Kernel B: MFMA smooth-softmax attention + residual 1 ----------------
// Block = 8 waves (512 thr), one 16-query tile; wave w handles keys [w*512, w*512+512).
// S^T via mfma(A=K-frag, B=Q-frag); its C layout feeds PV mfmas (O^T += V^T * P^T)
// directly after bf16 packing. V^T row 8 = ones -> C row 8 accumulates Z (exp path)
// and R (relu path): no scalar reductions at all. LDS combine across 8 waves.
__global__ __launch_bounds__(512) void attn_kernel(
        const ushort* __restrict__ QH, const ushort* __restrict__ KH,
        const ushort* __restrict__ VT, const float* __restrict__ x,
        float* __restrict__ Z1) {
    __shared__ f32x4 Le[8][64];
    __shared__ f32x4 Lr[8][64];

    const int tid  = threadIdx.x;
    const int w    = tid >> 6;        // 0..7
    const int lane = tid & 63;
    const int grp  = lane >> 4;
    const int qi   = lane & 15;
    const int q0   = blockIdx.x * 16;

    U2S4 qf;
    qf.u = *(const uint2*)(QH + (size_t)(q0 + qi) * 16 + 4 * grp);

    const ushort* kp = KH + (size_t)(w * 512 + qi) * 16 + 4 * grp;
    const ushort* vp = VT + (size_t)qi * NKV + w * 512 + 4 * grp;

    f32x4 ae = {0.f,0.f,0.f,0.f};
    f32x4 ar = {0.f,0.f,0.f,0.f};

    #pragma unroll 4
    for (int t = 0; t < 32; t++) {
        U2S4 kf; kf.u = *(const uint2*)kp;
        U2S4 vf; vf.u = *(const uint2*)vp;
        kp += 16 * 16;   // next 16 key rows
        vp += 16;        // next 16 key cols

        f32x4 s = MFMA16(kf.s, qf.s, ((f32x4){0.f,0.f,0.f,0.f}));

        float e0 = EXP2F(s[0]), e1 = EXP2F(s[1]);
        float e2 = EXP2F(s[2]), e3 = EXP2F(s[3]);
        float r0 = fmaxf(s[0], 0.f), r1 = fmaxf(s[1], 0.f);
        float r2 = fmaxf(s[2], 0.f), r3 = fmaxf(s[3], 0.f);

        U2S4 pe; pe.u.x = pk_bf16(e0, e1); pe.u.y = pk_bf16(e2, e3);
        U2S4 pr; pr.u.x = pk_bf16(r0, r1); pr.u.y = pk_bf16(r2, r3);

        ae = MFMA16(vf.s, pe.s, ae);
        ar = MFMA16(vf.s, pr.s, ar);
    }

    Le[w][lane] = ae;
    Lr[w][lane] = ar;
    __syncthreads();

    if (tid < 32) {                   // q = tid&15, g = tid>>4 -> d = 4g..4g+3
        const int q = tid & 15, g = tid >> 4;
        f32x4 Ae = {0.f,0.f,0.f,0.f}, Ar = {0.f,0.f,0.f,0.f};
        float Z = 0.f, R = 0.f;
        #pragma unroll
        for (int w2 = 0; w2 < 8; w2++) {
            f32x4 le = Le[w2][g*16+q], lr = Lr[w2][g*16+q];
            Ae += le; Ar += lr;
            Z += Le[w2][32+q][0];     // V^T row 8 (ones) = sum of exp weights
            R += Lr[w2][32+q][0];     // = sum of relu weights (x log2e)
        }
        float iz  = 1.0f / Z;
        float den = 1.0f / (C1 * R + 1.0f);
        const float4* xp = (const float4*)(x + (size_t)(q0 + q) * 8 + 4 * g);
        float4 xr = *xp;
        float4 o;
        o.x = (C1 * Ar[0] + Ae[0] * iz) * den + xr.x;
        o.y = (C1 * Ar[1] + Ae[1] * iz) * den + xr.y;
        o.z = (C1 * Ar[2] + Ae[2] * iz) * den + xr.z;
        o.w = (C1 * Ar[3] + Ae[3] * iz) * den + xr.w;
        *(float4*)(Z1 + (size_t)(q0 + q) * 8 + 4 * g) = o;
    }
}

// ---------------- Kernel C: LN + MLP (8->64->64->8) + residual 2 ----------------
// 8 threads per row (8 h2-units each, interleaved o = og + 8*oo); W2 in LDS with
// stride-68 padding (og-lanes land on distinct banks); butterfly combine over 8.
__global__ __launch_bounds__(256) void mlp_kernel(
        const float* __restrict__ Z1,
        const float* __restrict__ W1, const float* __restrict__ b1,
        const float* __restrict__ W2, const float* __restrict__ b2,
        const float* __restrict__ W3, const float* __restrict__ b3,
        const float* __restrict__ ln_w, const float* __restrict__ ln_b,
        float* __restrict__ out) {
    __shared__ float W1s[512], W2s[64*68], W3s[512], b1s[64], b2s[64], b3s[8], lw[8], lb[8];
    for (int i = threadIdx.x; i < 512; i += 256) { W1s[i] = W1[i]; W3s[i] = W3[i]; }
    for (int i = threadIdx.x; i < 4096; i += 256) W2s[(i >> 6) * 68 + (i & 63)] = W2[i];
    if (threadIdx.x < 64) { b1s[threadIdx.x] = b1[threadIdx.x]; b2s[threadIdx.x] = b2[threadIdx.x]; }
    if (threadIdx.x < 8) { b3s[threadIdx.x] = b3[threadIdx.x]; lw[threadIdx.x] = ln_w[threadIdx.x]; lb[threadIdx.x] = ln_b[threadIdx.x]; }
    __syncthreads();

    int gid = blockIdx.x * 256 + threadIdx.x;
    int row = gid >> 3;
    int og  = threadIdx.x & 7;        // 8 hidden-2 units each (interleaved)

    const float4* zp = (const float4*)(Z1 + (size_t)row * 8);
    float4 a = zp[0], b = zp[1];
    float z1r[8] = {a.x,a.y,a.z,a.w,b.x,b.y,b.z,b.w};
    float mu = 0.f;
    #pragma unroll
    for (int i = 0; i < 8; i++) mu += z1r[i];
    mu *= 0.125f;
    float var = 0.f;
    #pragma unroll
    for (int i = 0; i < 8; i++) { float d = z1r[i] - mu; var += d * d; }
    var *= 0.125f;
    float rs = rsqrtf(var + EPSF);
    float z2[8];
    #pragma unroll
    for (int i = 0; i < 8; i++) z2[i] = (z1r[i] - mu) * rs * lw[i] + lb[i];

    float h[64];
    #pragma unroll
    for (int o = 0; o < 64; o++) {
        float acc = b1s[o];
        #pragma unroll
        for (int i = 0; i < 8; i++) acc += W1s[o*8+i] * z2[i];
        h[o] = fmaxf(acc, 0.f);
    }

    float oacc[8];
    #pragma unroll
    for (int d = 0; d < 8; d++) oacc[d] = 0.f;
    #pragma unroll
    for (int oo = 0; oo < 8; oo++) {
        int o = og + 8 * oo;
        float a0 = 0.f, a1 = 0.f, a2 = 0.f, a3 = 0.f;
        const float4* w2r = (const float4*)(W2s + o * 68);
        #pragma unroll
        for (int i4 = 0; i4 < 16; i4++) {
            float4 wv = w2r[i4];
            a0 += wv.x * h[4*i4];   a1 += wv.y * h[4*i4+1];
            a2 += wv.z * h[4*i4+2]; a3 += wv.w * h[4*i4+3];
        }
        float act = fmaxf(b2s[o] + ((a0 + a1) + (a2 + a3)), 0.f);
        #pragma unroll
        for (int d = 0; d < 8; d++) oacc[d] += W3s[d*64+o] * act;
    }

    #pragma unroll
    for (int m = 1; m <= 4; m <<= 1) {
        #pragma unroll
        for (int d = 0; d < 8; d++) oacc[d] += __shfl_xor(oacc[d], m);
    }
    if (og == 0) {
        float4* op = (float4*)(out + (size_t)row * 8);
        op[0] = make_float4(oacc[0]+b3s[0]+z1r[0], oacc[1]+b3s[1]+z1r[1],
                            oacc[2]+b3s[2]+z1r[2], oacc[3]+b3s[3]+z1r[3]);
        op[1] = make_float4(oacc[4]+b3s[4]+z1r[4], oacc[5]+b3s[5]+z1r[5],
                            oacc[6]+b3s[6]+z1r[6], oacc[7]+b3s[7]+z1r[7]);
    }
}

extern "C" void kernel_launch(void* const* d_in, const int* in_sizes, int n_in,
                              void* d_out, int out_size, void* d_ws, size_t ws_size,
                              hipStream_t stream) {
    const float* x   = (const float*)d_in[0];
    const float* y   = (const float*)d_in[1];
    const float* Wq  = (const float*)d_in[2];
    const float* Wk  = (const float*)d_in[3];
    const float* Wv  = (const float*)d_in[4];
    const float* W1  = (const float*)d_in[5];
    const float* b1  = (const float*)d_in[6];
    const float* W2  = (const float*)d_in[7];
    const float* b2  = (const float*)d_in[8];
    const float* W3  = (const float*)d_in[9];
    const float* b3  = (const float*)d_in[10];
    const float* lnw = (const float*)d_in[11];
    const float* lnb = (const float*)d_in[12];

    char* ws = (char*)d_ws;
    ushort* QH = (ushort*)ws;                 // 524288 B
    ushort* KH = (ushort*)(ws + 524288);      // 131072 B
    ushort* VT = (ushort*)(ws + 655360);      // 131072 B
    float*  Z1 = (float*)(ws + 786432);       // 524288 B
    float* out = (float*)d_out;

    preproc_kernel<<<(NQ + NKV + 255) / 256, 256, 0, stream>>>(x, y, Wq, Wk, Wv, lnw, lnb, QH, KH, VT);
    attn_kernel<<<NQ / 16, 512, 0, stream>>>(QH, KH, VT, x, Z1);
    mlp_kernel<<<(NQ * 8) / 256, 256, 0, stream>>>(Z1, W1, b1, W2, b2, W3, b3, lnw, lnb, out);
}

// Round 4
// 37.674 us; speedup vs baseline: 3.3834x; 1.5582x over previous
//
#include <hip/hip_runtime.h>
#include <hip/hip_bf16.h>

#define NQ 16384
#define NKV 4096
#define EPSF 1e-5f
// 1/sqrt(8) * log2(e): folds the exp2 conversion into K-hat
#define SCALE2 0.5100604576761344f
// 0.1 / log2(e) = 0.1*ln2: compensates relu weights scaled by log2e
#define C1 0.06931471805599453f

typedef float f32x4 __attribute__((ext_vector_type(4)));
typedef short s16x4 __attribute__((ext_vector_type(4)));

union U2S4 { uint2 u; s16x4 s; };

#if __has_builtin(__builtin_amdgcn_mfma_f32_16x16x16bf16_1k)
#define MFMA16(a, b, c) __builtin_amdgcn_mfma_f32_16x16x16bf16_1k((a), (b), (c), 0, 0, 0)
#else
static __device__ __forceinline__ f32x4 mfma16_asm(s16x4 a, s16x4 b, f32x4 c) {
    asm volatile("v_mfma_f32_16x16x16_bf16 %0, %1, %2, %0" : "+v"(c) : "v"(a), "v"(b));
    return c;
}
#define MFMA16(a, b, c) mfma16_asm((a), (b), (c))
#endif

#if __has_builtin(__builtin_amdgcn_exp2f)
#define EXP2F(x) __builtin_amdgcn_exp2f(x)
#else
#define EXP2F(x) exp2f(x)
#endif

// native packed f32->bf16 (RNE); header path is a multi-instr integer sequence
__device__ __forceinline__ unsigned int pk_bf16(float a, float b) {
    unsigned int r;
    asm("v_cvt_pk_bf16_f32 %0, %1, %2" : "=v"(r) : "v"(a), "v"(b));
    return r;
}

// ---------------- Kernel A: LN + Q/K/V projections -> bf16 fragments ----------------
// QH:  [16384][16] bf16 (cols 8..15 zero)
// KH:  [4096][16] bf16 (scaled by log2e/sqrt8, cols 8..15 zero) = tile-contiguous 512B
// VTT: [256][16][16] bf16 tile-major: tile t, row d, col kc (key 16t+kc).
//      row 8 = ones (Z/R via MFMA), rows 9..15 = 0. 512B per tile, same
//      wave address pattern as KH -> fully coalesced 4-line loads.
__global__ void preproc_kernel(const float* __restrict__ x, const float* __restrict__ y,
                               const float* __restrict__ Wq, const float* __restrict__ Wk,
                               const float* __restrict__ Wv, const float* __restrict__ ln_w,
                               const float* __restrict__ ln_b,
                               ushort* __restrict__ QH, ushort* __restrict__ KH,
                               ushort* __restrict__ VTT) {
    int row = blockIdx.x * blockDim.x + threadIdx.x;
    if (row >= NQ + NKV) return;
    bool is_x = row < NQ;
    const float* src = is_x ? (x + (size_t)row * 8) : (y + (size_t)(row - NQ) * 8);
    float4 a = ((const float4*)src)[0];
    float4 b = ((const float4*)src)[1];
    float t[8] = {a.x,a.y,a.z,a.w,b.x,b.y,b.z,b.w};
    float mu = 0.f;
    #pragma unroll
    for (int i = 0; i < 8; i++) mu += t[i];
    mu *= 0.125f;
    float var = 0.f;
    #pragma unroll
    for (int i = 0; i < 8; i++) { float d = t[i] - mu; var += d * d; }
    var *= 0.125f;
    float rs = rsqrtf(var + EPSF);
    float z[8];
    #pragma unroll
    for (int i = 0; i < 8; i++) z[i] = (t[i] - mu) * rs * ln_w[i] + ln_b[i];

    if (is_x) {
        float o[8];
        #pragma unroll
        for (int oo = 0; oo < 8; oo++) {
            float acc = 0.f;
            #pragma unroll
            for (int i = 0; i < 8; i++) acc += Wq[oo*8+i] * z[i];
            o[oo] = acc;
        }
        uint4 lo, hi;
        lo.x = pk_bf16(o[0],o[1]); lo.y = pk_bf16(o[2],o[3]);
        lo.z = pk_bf16(o[4],o[5]); lo.w = pk_bf16(o[6],o[7]);
        hi.x = hi.y = hi.z = hi.w = 0u;
        uint4* dst = (uint4*)(QH + (size_t)row * 16);
        dst[0] = lo; dst[1] = hi;
    } else {
        int r = row - NQ;
        float ok[8], ov[8];
        #pragma unroll
        for (int oo = 0; oo < 8; oo++) {
            float ak = 0.f, av = 0.f;
            #pragma unroll
            for (int i = 0; i < 8; i++) { ak += Wk[oo*8+i]*z[i]; av += Wv[oo*8+i]*z[i]; }
            ok[oo] = ak * SCALE2; ov[oo] = av;
        }
        uint4 lo, hi;
        lo.x = pk_bf16(ok[0],ok[1]); lo.y = pk_bf16(ok[2],ok[3]);
        lo.z = pk_bf16(ok[4],ok[5]); lo.w = pk_bf16(ok[6],ok[7]);
        hi.x = hi.y = hi.z = hi.w = 0u;
        uint4* dst = (uint4*)(KH + (size_t)r * 16);
        dst[0] = lo; dst[1] = hi;

        ushort* vt = VTT + (size_t)(r >> 4) * 256 + (r & 15);
        #pragma unroll
        for (int d = 0; d < 8; d++) {
            unsigned int p = pk_bf16(ov[d], 0.f);
            vt[d * 16] = (ushort)(p & 0xFFFF);
        }
        vt[8 * 16] = 0x3F80;   // 1.0 -> Z/R accumulator row
        #pragma unroll
        for (int d = 9; d < 16; d++) vt[d * 16] = 0;
    }
}

// ---------------- Kernel B: MFMA smooth-softmax attention + residual 1 ----------------
// Block = 8 waves (512 thr), 32 queries (2 Q-fragments); wave w owns keys
// [w*512, w*512+512) = key-tiles w*32..w*32+31. Each iteration: ONE kf + ONE vf
// load (both 512B coalesced) feed 2 S-MFMAs and 4 PV-MFMAs. V row 8 = ones ->
// Z/R come out of the PV accumulators. Distance-1 register prefetch.
__global__ __launch_bounds__(512) void attn_kernel(
        const ushort* __restrict__ QH, const ushort* __restrict__ KH,
        const ushort* __restrict__ VTT, const float* __restrict__ x,
        float* __restrict__ Z1) {
    __shared__ f32x4 Le[8][2][64];
    __shared__ f32x4 Lr[8][2][64];

    const int tid  = threadIdx.x;
    const int w    = tid >> 6;        // 0..7
    const int lane = tid & 63;
    const int grp  = lane >> 4;
    const int qi   = lane & 15;
    const int q0   = blockIdx.x * 32;

    U2S4 qf0, qf1;
    qf0.u = *(const uint2*)(QH + (size_t)(q0 + qi) * 16 + 4 * grp);
    qf1.u = *(const uint2*)(QH + (size_t)(q0 + 16 + qi) * 16 + 4 * grp);

    const ushort* kp = KH  + (size_t)(w * 32) * 256 + qi * 16 + 4 * grp;
    const ushort* vp = VTT + (size_t)(w * 32) * 256 + qi * 16 + 4 * grp;

    f32x4 ae0 = {0.f,0.f,0.f,0.f}, ar0 = {0.f,0.f,0.f,0.f};
    f32x4 ae1 = {0.f,0.f,0.f,0.f}, ar1 = {0.f,0.f,0.f,0.f};

    U2S4 kf, vf, kfn, vfn;
    kf.u = *(const uint2*)kp;
    vf.u = *(const uint2*)vp;

    #pragma unroll 4
    for (int t = 0; t < 32; t++) {
        kp += 256; vp += 256;
        kfn.u = *(const uint2*)kp;    // prefetch next tile (last one over-reads
        vfn.u = *(const uint2*)vp;    // into the adjacent ws region: benign)

        f32x4 s0 = MFMA16(kf.s, qf0.s, ((f32x4){0.f,0.f,0.f,0.f}));
        f32x4 s1 = MFMA16(kf.s, qf1.s, ((f32x4){0.f,0.f,0.f,0.f}));

        float e00 = EXP2F(s0[0]), e01 = EXP2F(s0[1]), e02 = EXP2F(s0[2]), e03 = EXP2F(s0[3]);
        float e10 = EXP2F(s1[0]), e11 = EXP2F(s1[1]), e12 = EXP2F(s1[2]), e13 = EXP2F(s1[3]);
        float r00 = fmaxf(s0[0],0.f), r01 = fmaxf(s0[1],0.f), r02 = fmaxf(s0[2],0.f), r03 = fmaxf(s0[3],0.f);
        float r10 = fmaxf(s1[0],0.f), r11 = fmaxf(s1[1],0.f), r12 = fmaxf(s1[2],0.f), r13 = fmaxf(s1[3],0.f);

        U2S4 pe0, pr0, pe1, pr1;
        pe0.u.x = pk_bf16(e00,e01); pe0.u.y = pk_bf16(e02,e03);
        pe1.u.x = pk_bf16(e10,e11); pe1.u.y = pk_bf16(e12,e13);
        pr0.u.x = pk_bf16(r00,r01); pr0.u.y = pk_bf16(r02,r03);
        pr1.u.x = pk_bf16(r10,r11); pr1.u.y = pk_bf16(r12,r13);

        ae0 = MFMA16(vf.s, pe0.s, ae0);
        ar0 = MFMA16(vf.s, pr0.s, ar0);
        ae1 = MFMA16(vf.s, pe1.s, ae1);
        ar1 = MFMA16(vf.s, pr1.s, ar1);

        kf = kfn; vf = vfn;
    }

    Le[w][0][lane] = ae0; Le[w][1][lane] = ae1;
    Lr[w][0][lane] = ar0; Lr[w][1][lane] = ar1;
    __syncthreads();

    if (tid < 64) {                   // qloc = tid&31 (query in block), g = tid>>5 (d-half)
        const int qloc = tid & 31, g = tid >> 5;
        const int j = qloc >> 4, q = qloc & 15;
        f32x4 Ae = {0.f,0.f,0.f,0.f}, Ar = {0.f,0.f,0.f,0.f};
        float Z = 0.f, R = 0.f;
        #pragma unroll
        for (int w2 = 0; w2 < 8; w2++) {
            Ae += Le[w2][j][g*16+q];
            Ar += Lr[w2][j][g*16+q];
            Z  += Le[w2][j][32+q][0];   // C row 8 (ones row) = sum of exp weights
            R  += Lr[w2][j][32+q][0];   // = sum of relu weights (x log2e)
        }
        float iz  = 1.0f / Z;
        float den = 1.0f / (C1 * R + 1.0f);
        float4 xr = *(const float4*)(x + (size_t)(q0 + qloc) * 8 + 4 * g);
        float4 o;
        o.x = (C1 * Ar[0] + Ae[0] * iz) * den + xr.x;
        o.y = (C1 * Ar[1] + Ae[1] * iz) * den + xr.y;
        o.z = (C1 * Ar[2] + Ae[2] * iz) * den + xr.z;
        o.w = (C1 * Ar[3] + Ae[3] * iz) * den + xr.w;
        *(float4*)(Z1 + (size_t)(q0 + qloc) * 8 + 4 * g) = o;
    }
}

// ---------------- Kernel C: LN + MLP (8->64->64->8) + residual 2 ----------------
__global__ __launch_bounds__(256) void mlp_kernel(
        const float* __restrict__ Z1,
        const float* __restrict__ W1, const float* __restrict__ b1,
        const float* __restrict__ W2, const float* __restrict__ b2,
        const float* __restrict__ W3, const float* __restrict__ b3,
        const float* __restrict__ ln_w, const float* __restrict__ ln_b,
        float* __restrict__ out) {
    __shared__ float W1s[512], W2s[64*68], W3s[512], b1s[64], b2s[64], b3s[8], lw[8], lb[8];
    for (int i = threadIdx.x; i < 512; i += 256) { W1s[i] = W1[i]; W3s[i] = W3[i]; }
    for (int i = threadIdx.x; i < 4096; i += 256) W2s[(i >> 6) * 68 + (i & 63)] = W2[i];
    if (threadIdx.x < 64) { b1s[threadIdx.x] = b1[threadIdx.x]; b2s[threadIdx.x] = b2[threadIdx.x]; }
    if (threadIdx.x < 8) { b3s[threadIdx.x] = b3[threadIdx.x]; lw[threadIdx.x] = ln_w[threadIdx.x]; lb[threadIdx.x] = ln_b[threadIdx.x]; }
    __syncthreads();

    int gid = blockIdx.x * 256 + threadIdx.x;
    int row = gid >> 3;
    int og  = threadIdx.x & 7;        // 8 hidden-2 units each (interleaved)

    const float4* zp = (const float4*)(Z1 + (size_t)row * 8);
    float4 a = zp[0], b = zp[1];
    float z1r[8] = {a.x,a.y,a.z,a.w,b.x,b.y,b.z,b.w};
    float mu = 0.f;
    #pragma unroll
    for (int i = 0; i < 8; i++) mu += z1r[i];
    mu *= 0.125f;
    float var = 0.f;
    #pragma unroll
    for (int i = 0; i < 8; i++) { float d = z1r[i] - mu; var += d * d; }
    var *= 0.125f;
    float rs = rsqrtf(var + EPSF);
    float z2[8];
    #pragma unroll
    for (int i = 0; i < 8; i++) z2[i] = (z1r[i] - mu) * rs * lw[i] + lb[i];

    float h[64];
    #pragma unroll
    for (int o = 0; o < 64; o++) {
        float acc = b1s[o];
        #pragma unroll
        for (int i = 0; i < 8; i++) acc += W1s[o*8+i] * z2[i];
        h[o] = fmaxf(acc, 0.f);
    }

    float oacc[8];
    #pragma unroll
    for (int d = 0; d < 8; d++) oacc[d] = 0.f;
    #pragma unroll
    for (int oo = 0; oo < 8; oo++) {
        int o = og + 8 * oo;
        float a0 = 0.f, a1 = 0.f, a2 = 0.f, a3 = 0.f;
        const float4* w2r = (const float4*)(W2s + o * 68);
        #pragma unroll
        for (int i4 = 0; i4 < 16; i4++) {
            float4 wv = w2r[i4];
            a0 += wv.x * h[4*i4];   a1 += wv.y * h[4*i4+1];
            a2 += wv.z * h[4*i4+2]; a3 += wv.w * h[4*i4+3];
        }
        float act = fmaxf(b2s[o] + ((a0 + a1) + (a2 + a3)), 0.f);
        #pragma unroll
        for (int d = 0; d < 8; d++) oacc[d] += W3s[d*64+o] * act;
    }

    #pragma unroll
    for (int m = 1; m <= 4; m <<= 1) {
        #pragma unroll
        for (int d = 0; d < 8; d++) oacc[d] += __shfl_xor(oacc[d], m);
    }
    if (og == 0) {
        float4* op = (float4*)(out + (size_t)row * 8);
        op[0] = make_float4(oacc[0]+b3s[0]+z1r[0], oacc[1]+b3s[1]+z1r[1],
                            oacc[2]+b3s[2]+z1r[2], oacc[3]+b3s[3]+z1r[3]);
        op[1] = make_float4(oacc[4]+b3s[4]+z1r[4], oacc[5]+b3s[5]+z1r[5],
                            oacc[6]+b3s[6]+z1r[6], oacc[7]+b3s[7]+z1r[7]);
    }
}

extern "C" void kernel_launch(void* const* d_in, const int* in_sizes, int n_in,
                              void* d_out, int out_size, void* d_ws, size_t ws_size,
                              hipStream_t stream) {
    const float* x   = (const float*)d_in[0];
    const float* y   = (const float*)d_in[1];
    const float* Wq  = (const float*)d_in[2];
    const float* Wk  = (const float*)d_in[3];
    const float* Wv  = (const float*)d_in[4];
    const float* W1  = (const float*)d_in[5];
    const float* b1  = (const float*)d_in[6];
    const float* W2  = (const float*)d_in[7];
    const float* b2  = (const float*)d_in[8];
    const float* W3  = (const float*)d_in[9];
    const float* b3  = (const float*)d_in[10];
    const float* lnw = (const float*)d_in[11];
    const float* lnb = (const float*)d_in[12];

    char* ws = (char*)d_ws;
    ushort* QH  = (ushort*)ws;                 // 524288 B
    ushort* KH  = (ushort*)(ws + 524288);      // 131072 B
    ushort* VTT = (ushort*)(ws + 655360);      // 131072 B
    float*  Z1  = (float*)(ws + 786432);       // 524288 B
    float* out = (float*)d_out;

    preproc_kernel<<<(NQ + NKV + 255) / 256, 256, 0, stream>>>(x, y, Wq, Wk, Wv, lnw, lnb, QH, KH, VTT);
    attn_kernel<<<NQ / 32, 512, 0, stream>>>(QH, KH, VTT, x, Z1);
    mlp_kernel<<<(NQ * 8) / 256, 256, 0, stream>>>(Z1, W1, b1, W2, b2, W3, b3, lnw, lnb, out);
}

// Round 5
// 35.975 us; speedup vs baseline: 3.5432x; 1.0472x over previous
//
#include <hip/hip_runtime.h>
#include <hip/hip_bf16.h>

#define NQ 16384
#define NKV 4096
#define EPSF 1e-5f
// 1/sqrt(8) * log2(e): folds the exp2 conversion into K-hat
#define SCALE2 0.5100604576761344f
// 0.1 / log2(e) = 0.1*ln2: compensates relu weights scaled by log2e
#define C1 0.06931471805599453f

typedef float f32x4 __attribute__((ext_vector_type(4)));
typedef short s16x4 __attribute__((ext_vector_type(4)));

union U2S4 { uint2 u; s16x4 s; };

#if __has_builtin(__builtin_amdgcn_mfma_f32_16x16x16bf16_1k)
#define MFMA16(a, b, c) __builtin_amdgcn_mfma_f32_16x16x16bf16_1k((a), (b), (c), 0, 0, 0)
#else
static __device__ __forceinline__ f32x4 mfma16_asm(s16x4 a, s16x4 b, f32x4 c) {
    asm volatile("v_mfma_f32_16x16x16_bf16 %0, %1, %2, %0" : "+v"(c) : "v"(a), "v"(b));
    return c;
}
#define MFMA16(a, b, c) mfma16_asm((a), (b), (c))
#endif

#if __has_builtin(__builtin_amdgcn_exp2f)
#define EXP2F(x) __builtin_amdgcn_exp2f(x)
#else
#define EXP2F(x) exp2f(x)
#endif

// native packed f32->bf16 (RNE)
__device__ __forceinline__ unsigned int pk_bf16(float a, float b) {
    unsigned int r;
    asm("v_cvt_pk_bf16_f32 %0, %1, %2" : "=v"(r) : "v"(a), "v"(b));
    return r;
}

// ---------------- Kernel A: LN + Q/K/V projections -> bf16 fragments ----------------
// QH:  [16384][16] bf16 (cols 8..15 zero)
// KH:  [4096][16] bf16 (scaled by log2e/sqrt8, cols 8..15 zero) = tile-contiguous 512B
// VTT: [256][16][16] bf16 tile-major: tile t, row d, col kc (key 16t+kc).
//      row 8 = ones (Z/R via MFMA), rows 9..15 = 0.
__global__ void preproc_kernel(const float* __restrict__ x, const float* __restrict__ y,
                               const float* __restrict__ Wq, const float* __restrict__ Wk,
                               const float* __restrict__ Wv, const float* __restrict__ ln_w,
                               const float* __restrict__ ln_b,
                               ushort* __restrict__ QH, ushort* __restrict__ KH,
                               ushort* __restrict__ VTT) {
    int row = blockIdx.x * blockDim.x + threadIdx.x;
    if (row >= NQ + NKV) return;
    bool is_x = row < NQ;
    const float* src = is_x ? (x + (size_t)row * 8) : (y + (size_t)(row - NQ) * 8);
    float4 a = ((const float4*)src)[0];
    float4 b = ((const float4*)src)[1];
    float t[8] = {a.x,a.y,a.z,a.w,b.x,b.y,b.z,b.w};
    float mu = 0.f;
    #pragma unroll
    for (int i = 0; i < 8; i++) mu += t[i];
    mu *= 0.125f;
    float var = 0.f;
    #pragma unroll
    for (int i = 0; i < 8; i++) { float d = t[i] - mu; var += d * d; }
    var *= 0.125f;
    float rs = rsqrtf(var + EPSF);
    float z[8];
    #pragma unroll
    for (int i = 0; i < 8; i++) z[i] = (t[i] - mu) * rs * ln_w[i] + ln_b[i];

    if (is_x) {
        float o[8];
        #pragma unroll
        for (int oo = 0; oo < 8; oo++) {
            float acc = 0.f;
            #pragma unroll
            for (int i = 0; i < 8; i++) acc += Wq[oo*8+i] * z[i];
            o[oo] = acc;
        }
        uint4 lo, hi;
        lo.x = pk_bf16(o[0],o[1]); lo.y = pk_bf16(o[2],o[3]);
        lo.z = pk_bf16(o[4],o[5]); lo.w = pk_bf16(o[6],o[7]);
        hi.x = hi.y = hi.z = hi.w = 0u;
        uint4* dst = (uint4*)(QH + (size_t)row * 16);
        dst[0] = lo; dst[1] = hi;
    } else {
        int r = row - NQ;
        float ok[8], ov[8];
        #pragma unroll
        for (int oo = 0; oo < 8; oo++) {
            float ak = 0.f, av = 0.f;
            #pragma unroll
            for (int i = 0; i < 8; i++) { ak += Wk[oo*8+i]*z[i]; av += Wv[oo*8+i]*z[i]; }
            ok[oo] = ak * SCALE2; ov[oo] = av;
        }
        uint4 lo, hi;
        lo.x = pk_bf16(ok[0],ok[1]); lo.y = pk_bf16(ok[2],ok[3]);
        lo.z = pk_bf16(ok[4],ok[5]); lo.w = pk_bf16(ok[6],ok[7]);
        hi.x = hi.y = hi.z = hi.w = 0u;
        uint4* dst = (uint4*)(KH + (size_t)r * 16);
        dst[0] = lo; dst[1] = hi;

        ushort* vt = VTT + (size_t)(r >> 4) * 256 + (r & 15);
        #pragma unroll
        for (int d = 0; d < 8; d++) {
            unsigned int p = pk_bf16(ov[d], 0.f);
            vt[d * 16] = (ushort)(p & 0xFFFF);
        }
        vt[8 * 16] = 0x3F80;   // 1.0 -> Z/R accumulator row
        #pragma unroll
        for (int d = 9; d < 16; d++) vt[d * 16] = 0;
    }
}

// ---------------- Kernel B: MFMA smooth-softmax attention + residual 1 ----------------
// Block = 16 waves (1024 thr), 32 queries (2 Q-fragments); wave w owns key-tiles
// [w*16, w*16+16) (256 keys). Depth-2 software-pipelined K/V loads (512B coalesced).
// V row 8 = ones -> Z/R from the PV accumulators. LDS stores only the 48 useful
// C-lanes per wave/frag (rows 0..11 incl. row 8) -> 48KB block LDS, 2 blocks/CU.
__global__ __launch_bounds__(1024) void attn_kernel(
        const ushort* __restrict__ QH, const ushort* __restrict__ KH,
        const ushort* __restrict__ VTT, const float* __restrict__ x,
        float* __restrict__ Z1) {
    __shared__ f32x4 Le[16][2][48];
    __shared__ f32x4 Lr[16][2][48];

    const int tid  = threadIdx.x;
    const int w    = tid >> 6;        // 0..15
    const int lane = tid & 63;
    const int grp  = lane >> 4;
    const int qi   = lane & 15;
    const int q0   = blockIdx.x * 32;

    U2S4 qf0, qf1;
    qf0.u = *(const uint2*)(QH + (size_t)(q0 + qi) * 16 + 4 * grp);
    qf1.u = *(const uint2*)(QH + (size_t)(q0 + 16 + qi) * 16 + 4 * grp);

    const ushort* kp = KH  + (size_t)(w * 16) * 256 + qi * 16 + 4 * grp;
    const ushort* vp = VTT + (size_t)(w * 16) * 256 + qi * 16 + 4 * grp;

    f32x4 ae0 = {0.f,0.f,0.f,0.f}, ar0 = {0.f,0.f,0.f,0.f};
    f32x4 ae1 = {0.f,0.f,0.f,0.f}, ar1 = {0.f,0.f,0.f,0.f};

    // depth-2 pipeline (over-reads 2 tiles past range: lands in ws, benign)
    U2S4 k0, v0, k1, v1, k2, v2;
    k0.u = *(const uint2*)kp;        v0.u = *(const uint2*)vp;
    k1.u = *(const uint2*)(kp+256);  v1.u = *(const uint2*)(vp+256);
    kp += 512; vp += 512;

    #pragma unroll 8
    for (int t = 0; t < 16; t++) {
        k2.u = *(const uint2*)kp;  v2.u = *(const uint2*)vp;
        kp += 256; vp += 256;

        f32x4 s0 = MFMA16(k0.s, qf0.s, ((f32x4){0.f,0.f,0.f,0.f}));
        f32x4 s1 = MFMA16(k0.s, qf1.s, ((f32x4){0.f,0.f,0.f,0.f}));

        float e00 = EXP2F(s0[0]), e01 = EXP2F(s0[1]), e02 = EXP2F(s0[2]), e03 = EXP2F(s0[3]);
        float e10 = EXP2F(s1[0]), e11 = EXP2F(s1[1]), e12 = EXP2F(s1[2]), e13 = EXP2F(s1[3]);
        float r00 = fmaxf(s0[0],0.f), r01 = fmaxf(s0[1],0.f), r02 = fmaxf(s0[2],0.f), r03 = fmaxf(s0[3],0.f);
        float r10 = fmaxf(s1[0],0.f), r11 = fmaxf(s1[1],0.f), r12 = fmaxf(s1[2],0.f), r13 = fmaxf(s1[3],0.f);

        U2S4 pe0, pr0, pe1, pr1;
        pe0.u.x = pk_bf16(e00,e01); pe0.u.y = pk_bf16(e02,e03);
        pe1.u.x = pk_bf16(e10,e11); pe1.u.y = pk_bf16(e12,e13);
        pr0.u.x = pk_bf16(r00,r01); pr0.u.y = pk_bf16(r02,r03);
        pr1.u.x = pk_bf16(r10,r11); pr1.u.y = pk_bf16(r12,r13);

        ae0 = MFMA16(v0.s, pe0.s, ae0);
        ar0 = MFMA16(v0.s, pr0.s, ar0);
        ae1 = MFMA16(v0.s, pe1.s, ae1);
        ar1 = MFMA16(v0.s, pr1.s, ar1);

        k0 = k1; v0 = v1;
        k1 = k2; v1 = v2;
    }

    if (grp < 3) {                    // lanes 0..47: rows 0..11 (all we consume)
        Le[w][0][lane] = ae0; Le[w][1][lane] = ae1;
        Lr[w][0][lane] = ar0; Lr[w][1][lane] = ar1;
    }
    __syncthreads();

    if (tid < 64) {                   // qloc = tid&31, g = tid>>5 (d-half)
        const int qloc = tid & 31, g = tid >> 5;
        const int j = qloc >> 4, q = qloc & 15;
        f32x4 Ae = {0.f,0.f,0.f,0.f}, Ar = {0.f,0.f,0.f,0.f};
        float Z = 0.f, R = 0.f;
        #pragma unroll
        for (int w2 = 0; w2 < 16; w2++) {
            Ae += Le[w2][j][g*16+q];
            Ar += Lr[w2][j][g*16+q];
            Z  += Le[w2][j][32+q][0];   // C row 8 (ones row) = sum of exp weights
            R  += Lr[w2][j][32+q][0];   // = sum of relu weights (x log2e)
        }
        float iz  = 1.0f / Z;
        float den = 1.0f / (C1 * R + 1.0f);
        float4 xr = *(const float4*)(x + (size_t)(q0 + qloc) * 8 + 4 * g);
        float4 o;
        o.x = (C1 * Ar[0] + Ae[0] * iz) * den + xr.x;
        o.y = (C1 * Ar[1] + Ae[1] * iz) * den + xr.y;
        o.z = (C1 * Ar[2] + Ae[2] * iz) * den + xr.z;
        o.w = (C1 * Ar[3] + Ae[3] * iz) * den + xr.w;
        *(float4*)(Z1 + (size_t)(q0 + qloc) * 8 + 4 * g) = o;
    }
}

// ---------------- Kernel C: LN + MLP (8->64->64->8) + residual 2 ----------------
__global__ __launch_bounds__(256) void mlp_kernel(
        const float* __restrict__ Z1,
        const float* __restrict__ W1, const float* __restrict__ b1,
        const float* __restrict__ W2, const float* __restrict__ b2,
        const float* __restrict__ W3, const float* __restrict__ b3,
        const float* __restrict__ ln_w, const float* __restrict__ ln_b,
        float* __restrict__ out) {
    __shared__ float W1s[512], W2s[64*68], W3s[512], b1s[64], b2s[64], b3s[8], lw[8], lb[8];
    for (int i = threadIdx.x; i < 512; i += 256) { W1s[i] = W1[i]; W3s[i] = W3[i]; }
    for (int i = threadIdx.x; i < 4096; i += 256) W2s[(i >> 6) * 68 + (i & 63)] = W2[i];
    if (threadIdx.x < 64) { b1s[threadIdx.x] = b1[threadIdx.x]; b2s[threadIdx.x] = b2[threadIdx.x]; }
    if (threadIdx.x < 8) { b3s[threadIdx.x] = b3[threadIdx.x]; lw[threadIdx.x] = ln_w[threadIdx.x]; lb[threadIdx.x] = ln_b[threadIdx.x]; }
    __syncthreads();

    int gid = blockIdx.x * 256 + threadIdx.x;
    int row = gid >> 3;
    int og  = threadIdx.x & 7;        // 8 hidden-2 units each (interleaved)

    const float4* zp = (const float4*)(Z1 + (size_t)row * 8);
    float4 a = zp[0], b = zp[1];
    float z1r[8] = {a.x,a.y,a.z,a.w,b.x,b.y,b.z,b.w};
    float mu = 0.f;
    #pragma unroll
    for (int i = 0; i < 8; i++) mu += z1r[i];
    mu *= 0.125f;
    float var = 0.f;
    #pragma unroll
    for (int i = 0; i < 8; i++) { float d = z1r[i] - mu; var += d * d; }
    var *= 0.125f;
    float rs = rsqrtf(var + EPSF);
    float z2[8];
    #pragma unroll
    for (int i = 0; i < 8; i++) z2[i] = (z1r[i] - mu) * rs * lw[i] + lb[i];

    float h[64];
    #pragma unroll
    for (int o = 0; o < 64; o++) {
        float acc = b1s[o];
        #pragma unroll
        for (int i = 0; i < 8; i++) acc += W1s[o*8+i] * z2[i];
        h[o] = fmaxf(acc, 0.f);
    }

    float oacc[8];
    #pragma unroll
    for (int d = 0; d < 8; d++) oacc[d] = 0.f;
    #pragma unroll
    for (int oo = 0; oo < 8; oo++) {
        int o = og + 8 * oo;
        float a0 = 0.f, a1 = 0.f, a2 = 0.f, a3 = 0.f;
        const float4* w2r = (const float4*)(W2s + o * 68);
        #pragma unroll
        for (int i4 = 0; i4 < 16; i4++) {
            float4 wv = w2r[i4];
            a0 += wv.x * h[4*i4];   a1 += wv.y * h[4*i4+1];
            a2 += wv.z * h[4*i4+2]; a3 += wv.w * h[4*i4+3];
        }
        float act = fmaxf(b2s[o] + ((a0 + a1) + (a2 + a3)), 0.f);
        #pragma unroll
        for (int d = 0; d < 8; d++) oacc[d] += W3s[d*64+o] * act;
    }

    #pragma unroll
    for (int m = 1; m <= 4; m <<= 1) {
        #pragma unroll
        for (int d = 0; d < 8; d++) oacc[d] += __shfl_xor(oacc[d], m);
    }
    if (og == 0) {
        float4* op = (float4*)(out + (size_t)row * 8);
        op[0] = make_float4(oacc[0]+b3s[0]+z1r[0], oacc[1]+b3s[1]+z1r[1],
                            oacc[2]+b3s[2]+z1r[2], oacc[3]+b3s[3]+z1r[3]);
        op[1] = make_float4(oacc[4]+b3s[4]+z1r[4], oacc[5]+b3s[5]+z1r[5],
                            oacc[6]+b3s[6]+z1r[6], oacc[7]+b3s[7]+z1r[7]);
    }
}

extern "C" void kernel_launch(void* const* d_in, const int* in_sizes, int n_in,
                              void* d_out, int out_size, void* d_ws, size_t ws_size,
                              hipStream_t stream) {
    const float* x   = (const float*)d_in[0];
    const float* y   = (const float*)d_in[1];
    const float* Wq  = (const float*)d_in[2];
    const float* Wk  = (const float*)d_in[3];
    const float* Wv  = (const float*)d_in[4];
    const float* W1  = (const float*)d_in[5];
    const float* b1  = (const float*)d_in[6];
    const float* W2  = (const float*)d_in[7];
    const float* b2  = (const float*)d_in[8];
    const float* W3  = (const float*)d_in[9];
    const float* b3  = (const float*)d_in[10];
    const float* lnw = (const float*)d_in[11];
    const float* lnb = (const float*)d_in[12];

    char* ws = (char*)d_ws;
    ushort* QH  = (ushort*)ws;                 // 524288 B
    ushort* KH  = (ushort*)(ws + 524288);      // 131072 B
    ushort* VTT = (ushort*)(ws + 655360);      // 131072 B
    float*  Z1  = (float*)(ws + 786432);       // 524288 B
    float* out = (float*)d_out;

    preproc_kernel<<<(NQ + NKV + 255) / 256, 256, 0, stream>>>(x, y, Wq, Wk, Wv, lnw, lnb, QH, KH, VTT);
    attn_kernel<<<NQ / 32, 1024, 0, stream>>>(QH, KH, VTT, x, Z1);
    mlp_kernel<<<(NQ * 8) / 256, 256, 0, stream>>>(Z1, W1, b1, W2, b2, W3, b3, lnw, lnb, out);
}